// Round 10
// baseline (559.195 us; speedup 1.0000x reference)
//
#include <hip/hip_runtime.h>
#include <hip/hip_fp16.h>
#include <cstdint>
#include <cstddef>

#define N_NODES 100000
#define N_EDGES 1600000
#define EPS 1e-5f

typedef _Float16 half8 __attribute__((ext_vector_type(8)));
typedef float floatx4 __attribute__((ext_vector_type(4)));

// LDS-binned histogram: ushort counters packed 2/uint (per-chunk count <= 25000 < 65536).
#define HCH 64                   // edge chunks
#define HRG 4                    // bin ranges
#define HBINS 32768              // ushort bins per range
#define HWORDS (HBINS / 2)       // 16384 uints = 64 KB LDS
#define HCHUNK (N_EDGES / HCH)   // 25000 edges per chunk
#define HCHUNK4 (HCHUNK / 4)     // 6250 int4 per chunk

// ---------------- graph prep (no device-scope atomics) ----------------
__global__ void k_hist_part(const int* __restrict__ keys, unsigned int* __restrict__ Hpart) {
  __shared__ unsigned int bins[HWORDS];
  int c = blockIdx.x % HCH, r = blockIdx.x / HCH;
  int base = r * HBINS;
  for (int i = threadIdx.x; i < HWORDS; i += 256) bins[i] = 0;
  __syncthreads();
  const int4* k4 = (const int4*)(keys + c * HCHUNK);
  for (int i = threadIdx.x; i < HCHUNK4; i += 256) {
    int4 k = k4[i];
    int a;
    a = k.x - base; if ((unsigned)a < (unsigned)HBINS) atomicAdd(&bins[a >> 1], 1u << ((a & 1) * 16));
    a = k.y - base; if ((unsigned)a < (unsigned)HBINS) atomicAdd(&bins[a >> 1], 1u << ((a & 1) * 16));
    a = k.z - base; if ((unsigned)a < (unsigned)HBINS) atomicAdd(&bins[a >> 1], 1u << ((a & 1) * 16));
    a = k.w - base; if ((unsigned)a < (unsigned)HBINS) atomicAdd(&bins[a >> 1], 1u << ((a & 1) * 16));
  }
  __syncthreads();
  unsigned int* outp = Hpart + ((size_t)blockIdx.x << 14);
  for (int i = threadIdx.x; i < HWORDS; i += 256) outp[i] = bins[i];
}

// Fused: src-histogram sum (-> out_norm) + dst-histogram exclusive scan (-> per-chunk
// bases, degd, in_norm) + per-256-node block sum for row_start scan.
__global__ void k_hist_scan2(const unsigned short* __restrict__ Hs,
                             unsigned short* __restrict__ Hd,
                             int* __restrict__ degd, float* __restrict__ out_norm,
                             float* __restrict__ in_norm, int* __restrict__ bsum) {
  __shared__ int sred[256];
  int t = threadIdx.x;
  int b = blockIdx.x * 256 + t;
  int total = 0;
  if (b < N_NODES) {
    int r = b >> 15, lo = b & (HBINS - 1);
    const unsigned short* ps = Hs + ((size_t)(r * HCH) << 15) + lo;
    unsigned int ds = 0;
#pragma unroll 8
    for (int c = 0; c < HCH; ++c) ds += ps[(size_t)c << 15];
    unsigned short* pd = Hd + ((size_t)(r * HCH) << 15) + lo;
    unsigned int tt = 0;
#pragma unroll 8
    for (int c = 0; c < HCH; ++c) {
      unsigned int v = pd[(size_t)c << 15];
      pd[(size_t)c << 15] = (unsigned short)tt;
      tt += v;
    }
    total = (int)tt;
    degd[b] = total;
    out_norm[b] = rsqrtf((float)max((int)ds, 1));
    in_norm[b] = rsqrtf((float)max(total, 1));
  }
  sred[t] = total;
  __syncthreads();
  for (int off = 128; off > 0; off >>= 1) {
    if (t < off) sred[t] += sred[t + off];
    __syncthreads();
  }
  if (t == 0) bsum[blockIdx.x] = sred[0];
}

__global__ void k_build(const int* __restrict__ src, const int* __restrict__ dst,
                        const unsigned short* __restrict__ Hbase,
                        const int* __restrict__ row_start, int* __restrict__ col) {
  __shared__ unsigned int cur[HWORDS];
  int c = blockIdx.x % HCH, r = blockIdx.x / HCH;
  int base = r * HBINS;
  for (int i = threadIdx.x; i < HWORDS; i += 256) cur[i] = 0;
  __syncthreads();
  const unsigned short* hb = Hbase + ((size_t)blockIdx.x << 15);
  const int4* d4 = (const int4*)(dst + c * HCHUNK);
  const int4* s4 = (const int4*)(src + c * HCHUNK);
  for (int i = threadIdx.x; i < HCHUNK4; i += 256) {
    int4 d = d4[i];
    int4 s = s4[i];
    int a;
    a = d.x - base;
    if ((unsigned)a < (unsigned)HBINS) {
      unsigned old = atomicAdd(&cur[a >> 1], 1u << ((a & 1) * 16));
      unsigned lr = (old >> ((a & 1) * 16)) & 0xffffu;
      col[row_start[d.x] + hb[a] + lr] = s.x;
    }
    a = d.y - base;
    if ((unsigned)a < (unsigned)HBINS) {
      unsigned old = atomicAdd(&cur[a >> 1], 1u << ((a & 1) * 16));
      unsigned lr = (old >> ((a & 1) * 16)) & 0xffffu;
      col[row_start[d.y] + hb[a] + lr] = s.y;
    }
    a = d.z - base;
    if ((unsigned)a < (unsigned)HBINS) {
      unsigned old = atomicAdd(&cur[a >> 1], 1u << ((a & 1) * 16));
      unsigned lr = (old >> ((a & 1) * 16)) & 0xffffu;
      col[row_start[d.z] + hb[a] + lr] = s.z;
    }
    a = d.w - base;
    if ((unsigned)a < (unsigned)HBINS) {
      unsigned old = atomicAdd(&cur[a >> 1], 1u << ((a & 1) * 16));
      unsigned lr = (old >> ((a & 1) * 16)) & 0xffffu;
      col[row_start[d.w] + hb[a] + lr] = s.w;
    }
  }
}

__global__ void k_scan2(int* bsum, int nb) {
  __shared__ int s[512];
  int t = threadIdx.x;
  int v = (t < nb) ? bsum[t] : 0;
  s[t] = v;
  __syncthreads();
  for (int off = 1; off < 512; off <<= 1) {
    int x = (t >= off) ? s[t - off] : 0;
    __syncthreads();
    s[t] += x;
    __syncthreads();
  }
  if (t < nb) bsum[t] = s[t] - v;  // exclusive
}

__global__ void k_scan3(const int* __restrict__ degd, const int* __restrict__ bsum,
                        int* row_start) {
  __shared__ int s[256];
  int t = threadIdx.x;
  int i = blockIdx.x * 256 + t;
  int v = (i < N_NODES) ? degd[i] : 0;
  s[t] = v;
  __syncthreads();
  for (int off = 1; off < 256; off <<= 1) {
    int x = (t >= off) ? s[t - off] : 0;
    __syncthreads();
    s[t] += x;
    __syncthreads();
  }
  if (i < N_NODES) row_start[i] = bsum[blockIdx.x] + s[t] - v;
  if (i == 0) row_start[N_NODES] = N_EDGES;
}

// ---------------- weights -> fp16, once per launch ----------------
// Layout (halves): w0@0, l0@16384, w1@32768, l1@49152, w2@65536, l2@70656 (total 75776)
__global__ void k_w2h(const float* __restrict__ w0, const float* __restrict__ l0,
                      const float* __restrict__ w1, const float* __restrict__ l1,
                      const float* __restrict__ w2, const float* __restrict__ l2,
                      unsigned short* __restrict__ W) {
  int i = blockIdx.x * 256 + threadIdx.x;  // float4 index
  if (i >= 18944) return;
  int h = i * 4;
  const float* src; int off;
  if (h < 16384)      { src = w0; off = h; }
  else if (h < 32768) { src = l0; off = h - 16384; }
  else if (h < 49152) { src = w1; off = h - 32768; }
  else if (h < 65536) { src = l1; off = h - 49152; }
  else if (h < 70656) { src = w2; off = h - 65536; }
  else                { src = l2; off = h - 70656; }
  float4 v = *(const float4*)(src + off);
  ushort4 o;
  o.x = __half_as_ushort(__float2half_rn(v.x));
  o.y = __half_as_ushort(__float2half_rn(v.y));
  o.z = __half_as_ushort(__float2half_rn(v.z));
  o.w = __half_as_ushort(__float2half_rn(v.w));
  ((ushort4*)W)[i] = o;
}

// ---------------- feat -> fp16 table (unscaled) ----
__global__ void k_feat2h(const float* __restrict__ feat, unsigned short* __restrict__ F) {
  int i = blockIdx.x * 256 + threadIdx.x;  // float4 index
  if (i >= N_NODES * 32) return;
  float4 v = ((const float4*)feat)[i];
  ushort4 u;
  u.x = __half_as_ushort(__float2half_rn(v.x));
  u.y = __half_as_ushort(__float2half_rn(v.y));
  u.z = __half_as_ushort(__float2half_rn(v.z));
  u.w = __half_as_ushort(__float2half_rn(v.w));
  ((ushort4*)F)[i] = u;
}

// ---------------- aggregation: quarter-wave gather (16 lanes x uint4 = one 256B row).
// out[d] = in_norm[d] * sum_e out_norm[src] * act(X[src]); act = fp32 BN+ReLU (BN=1) or id.
template<int BN>
__global__ void k_agg128h(const unsigned short* __restrict__ X, const int* __restrict__ col,
                          const int* __restrict__ row_start,
                          const float* __restrict__ out_norm,
                          const float* __restrict__ in_norm,
                          const float* __restrict__ stats,
                          const float* __restrict__ g, const float* __restrict__ bb,
                          unsigned short* __restrict__ out16) {
  int t = threadIdx.x;
  int lane = t & 63;
  int sub = lane & 15;  // 16 lanes x 16B cover the 256B row
  float scR[8], shR[8];
  if constexpr (BN) {
    __shared__ float scA[128], shA[128];
    if (t < 128) {
      const float inv = 1.f / (float)N_NODES;
      float mu = stats[t] * inv;
      float var = stats[128 + t] * inv - mu * mu;
      float s = rsqrtf(var + EPS) * g[t];
      scA[t] = s;
      shA[t] = bb[t] - mu * s;
    }
    __syncthreads();
#pragma unroll
    for (int j = 0; j < 8; ++j) { scR[j] = scA[sub * 8 + j]; shR[j] = shA[sub * 8 + j]; }
  }
  int wave = t >> 6;
  int node = blockIdx.x * 4 + wave;
  if (node >= N_NODES) return;
  int q = lane >> 4;    // quarter 0..3 — each quarter walks edges s0+q, s0+q+4, ...
  int s0 = row_start[node], s1 = row_start[node + 1];
  const uint4* hp = (const uint4*)X;  // row = 16 uint4
  float a[8];
#pragma unroll
  for (int j = 0; j < 8; ++j) a[j] = 0.f;
  int e = s0 + q;
  for (; e + 4 < s1; e += 8) {
    int c0 = col[e];
    int c1 = col[e + 4];
    float on0 = out_norm[c0];
    float on1 = out_norm[c1];
    uint4 u0 = hp[(size_t)c0 * 16 + sub];
    uint4 u1 = hp[(size_t)c1 * 16 + sub];
    const __half2* h0 = (const __half2*)&u0;
    const __half2* h1 = (const __half2*)&u1;
#pragma unroll
    for (int j = 0; j < 4; ++j) {
      float2 f0 = __half22float2(h0[j]);
      float2 f1 = __half22float2(h1[j]);
      if constexpr (BN) {
        f0.x = fmaxf(f0.x * scR[2 * j] + shR[2 * j], 0.f);
        f0.y = fmaxf(f0.y * scR[2 * j + 1] + shR[2 * j + 1], 0.f);
        f1.x = fmaxf(f1.x * scR[2 * j] + shR[2 * j], 0.f);
        f1.y = fmaxf(f1.y * scR[2 * j + 1] + shR[2 * j + 1], 0.f);
      }
      a[2 * j] += on0 * f0.x + on1 * f1.x;
      a[2 * j + 1] += on0 * f0.y + on1 * f1.y;
    }
  }
  if (e < s1) {
    int c = col[e];
    float on = out_norm[c];
    uint4 u = hp[(size_t)c * 16 + sub];
    const __half2* h0 = (const __half2*)&u;
#pragma unroll
    for (int j = 0; j < 4; ++j) {
      float2 f = __half22float2(h0[j]);
      if constexpr (BN) {
        f.x = fmaxf(f.x * scR[2 * j] + shR[2 * j], 0.f);
        f.y = fmaxf(f.y * scR[2 * j + 1] + shR[2 * j + 1], 0.f);
      }
      a[2 * j] += on * f.x;
      a[2 * j + 1] += on * f.y;
    }
  }
  // combine quarters (same sub -> same row components)
#pragma unroll
  for (int j = 0; j < 8; ++j) {
    a[j] += __shfl_xor(a[j], 16);
    a[j] += __shfl_xor(a[j], 32);
  }
  if (q == 0) {
    float sc = in_norm[node];
    __half2 o[4];
#pragma unroll
    for (int j = 0; j < 4; ++j)
      o[j] = __float22half2_rn(make_float2(a[2 * j] * sc, a[2 * j + 1] * sc));
    ((uint4*)out16)[(size_t)node * 16 + sub] = *(const uint4*)o;
  }
}

// ---------------- MFMA dual GEMM + fused BN stats. BM=128, 512 threads (8 waves x 16 rows):
// per-thread state identical to the proven BM=64 config (acc[8], av[4]); weight staging
// amortized 2x; per-wave stats rows; LDS-transpose coalesced epilogue.
template<int BN>
__launch_bounds__(512)
__global__ void k_gemm_dual16(const unsigned short* __restrict__ Xa,
                              const unsigned short* __restrict__ Xh,
                              const float* __restrict__ stats,
                              const float* __restrict__ g, const float* __restrict__ bb,
                              const unsigned short* __restrict__ W16,  // [2][128][128] fp16
                              unsigned short* __restrict__ Out16, float* __restrict__ pstats) {
  __shared__ __align__(16) unsigned short smem[128 * 136];  // sW compute / sT epilogue
  __shared__ float scA[128], shA[128];
  int t = threadIdx.x;               // 0..511
  int row0 = blockIdx.x * 128;
  int w = t >> 6, lane = t & 63;     // w 0..7
  int q = lane >> 4, m = lane & 15;
  if (BN && t < 128) {
    const float inv = 1.f / (float)N_NODES;
    float mu = stats[t] * inv;
    float var = stats[128 + t] * inv - mu * mu;
    float s = rsqrtf(var + EPS) * g[t];
    scA[t] = s;
    shA[t] = bb[t] - mu * s;
  }
  size_t arow = (size_t)min(row0 + w * 16 + m, N_NODES - 1);
  floatx4 acc[8];
#pragma unroll
  for (int i = 0; i < 8; ++i) acc[i] = (floatx4){0.f, 0.f, 0.f, 0.f};

  for (int phase = 0; phase < 2; ++phase) {
    const unsigned short* Xg = phase ? Xh : Xa;
    const uint4* xr = (const uint4*)Xg + arow * 16 + q;   // + ks*4
    uint4 av[4];
    av[0] = xr[0]; av[1] = xr[4]; av[2] = xr[8]; av[3] = xr[12];  // in flight over staging
    __syncthreads();  // phase 1: previous sW reads done; orders scA writes
    {
      const uint4* wsrc = (const uint4*)(W16 + ((size_t)phase << 14));
#pragma unroll
      for (int it = 0; it < 4; ++it) {
        int idx = it * 512 + t;          // 0..2047, fully coalesced
        *(uint4*)&smem[(idx >> 4) * 136 + (idx & 15) * 8] = wsrc[idx];
      }
    }
    if (BN && phase == 1) {
#pragma unroll
      for (int ks = 0; ks < 4; ++ks) {
        int kk = ks * 32 + q * 8;
        __half2* hh = (__half2*)&av[ks];
#pragma unroll
        for (int j = 0; j < 4; ++j) {
          float2 f = __half22float2(hh[j]);
          f.x = fmaxf(f.x * scA[kk + 2 * j] + shA[kk + 2 * j], 0.f);
          f.y = fmaxf(f.y * scA[kk + 2 * j + 1] + shA[kk + 2 * j + 1], 0.f);
          hh[j] = __float22half2_rn(f);
        }
      }
    }
    __syncthreads();
#pragma unroll
    for (int ks = 0; ks < 4; ++ks) {
      half8 a = *(half8*)&av[ks];
      int kk = ks * 32 + q * 8;
#pragma unroll
      for (int t8 = 0; t8 < 8; ++t8) {
        half8 b = *(const half8*)&smem[(t8 * 16 + m) * 136 + kk];
        acc[t8] = __builtin_amdgcn_mfma_f32_16x16x32_f16(a, b, acc[t8], 0, 0, 0);
      }
    }
  }
  // per-wave BN partial stats -> pstats row (blockIdx*8+w)
#pragma unroll
  for (int t8 = 0; t8 < 8; ++t8) {
    float s = 0.f, sq = 0.f;
#pragma unroll
    for (int i = 0; i < 4; ++i) {
      int row = row0 + w * 16 + q * 4 + i;
      if (row < N_NODES) {
        float v = acc[t8][i];
        s += v; sq += v * v;
      }
    }
    s += __shfl_xor(s, 16);
    s += __shfl_xor(s, 32);
    sq += __shfl_xor(sq, 16);
    sq += __shfl_xor(sq, 32);
    if (q == 0) {
      int c = t8 * 16 + m;
      pstats[((size_t)blockIdx.x * 8 + w) * 256 + c] = s;
      pstats[((size_t)blockIdx.x * 8 + w) * 256 + 128 + c] = sq;
    }
  }
  __syncthreads();  // all MFMA reads of sW done -> safe to alias
  unsigned short* sT = smem;  // [128][136]
#pragma unroll
  for (int t8 = 0; t8 < 8; ++t8) {
    int c = t8 * 16 + m;
#pragma unroll
    for (int i = 0; i < 4; ++i) {
      int r = w * 16 + q * 4 + i;
      sT[r * 136 + c] = __half_as_ushort(__float2half_rn(acc[t8][i]));
    }
  }
  __syncthreads();
  // coalesced uint4 stores (4 per thread)
#pragma unroll
  for (int it = 0; it < 4; ++it) {
    int idx = it * 512 + t;  // 0..2047
    int r = idx >> 4, gg = idx & 15;
    int row = row0 + r;
    if (row < N_NODES)
      *(uint4*)&Out16[(size_t)row * 128 + gg * 8] = *(const uint4*)&sT[r * 136 + gg * 8];
  }
}

// ---------------- stats reduction: [nblk][256] -> [256]
__global__ void k_stats_red(const float* __restrict__ pstats, float* __restrict__ stats,
                            int nblk) {
  int t = threadIdx.x;
  float s = 0.f;
  for (int b = blockIdx.x; b < nblk; b += gridDim.x)
    s += pstats[(size_t)b * 256 + t];
  atomicAdd(&stats[t], s);  // 32 blocks x 256 = 8K atomics total, negligible
}

// ---------------- MFMA layer-2 GEMM on h2 = BN+ReLU(P1) (folded):
//   p = fp16(out_norm*(h2@w2^T)) [stride 64, zero-padded]; out = h2@l2^T + b2.
__launch_bounds__(256)
__global__ void k_gemm2_16(const unsigned short* __restrict__ X,  // P1 pre-BN
                           const float* __restrict__ stats,
                           const float* __restrict__ g, const float* __restrict__ bb,
                           const unsigned short* __restrict__ W80,  // [80][128] fp16: w2 then l2
                           const float* __restrict__ b2,
                           const float* __restrict__ out_norm,
                           __half* __restrict__ p, float* __restrict__ out) {
  __shared__ __align__(16) unsigned short smem[80 * 136];  // sW compute / sTp+sTo epilogue
  __shared__ float scA[128], shA[128];
  int t = threadIdx.x;
  int row0 = blockIdx.x * 64;
  int w = t >> 6, lane = t & 63;
  int q = lane >> 4, m = lane & 15;
  if (t < 128) {
    const float inv = 1.f / (float)N_NODES;
    float mu = stats[t] * inv;
    float var = stats[128 + t] * inv - mu * mu;
    float s = rsqrtf(var + EPS) * g[t];
    scA[t] = s;
    shA[t] = bb[t] - mu * s;
  }
  size_t arow = (size_t)min(row0 + w * 16 + m, N_NODES - 1);
  const uint4* xr = (const uint4*)X + arow * 16 + q;
  uint4 av[4];
  av[0] = xr[0]; av[1] = xr[4]; av[2] = xr[8]; av[3] = xr[12];
  {
    const uint4* wsrc = (const uint4*)W80;  // 80*16 = 1280 uint4
#pragma unroll
    for (int it = 0; it < 5; ++it) {
      int idx = it * 256 + t;
      *(uint4*)&smem[(idx >> 4) * 136 + (idx & 15) * 8] = wsrc[idx];
    }
  }
  __syncthreads();
  // fold BN+ReLU into A-fragments
#pragma unroll
  for (int ks = 0; ks < 4; ++ks) {
    int kk = ks * 32 + q * 8;
    __half2* hh = (__half2*)&av[ks];
#pragma unroll
    for (int j = 0; j < 4; ++j) {
      float2 f = __half22float2(hh[j]);
      f.x = fmaxf(f.x * scA[kk + 2 * j] + shA[kk + 2 * j], 0.f);
      f.y = fmaxf(f.y * scA[kk + 2 * j + 1] + shA[kk + 2 * j + 1], 0.f);
      hh[j] = __float22half2_rn(f);
    }
  }
  floatx4 acc[5];
#pragma unroll
  for (int i = 0; i < 5; ++i) acc[i] = (floatx4){0.f, 0.f, 0.f, 0.f};
#pragma unroll
  for (int ks = 0; ks < 4; ++ks) {
    half8 a = *(half8*)&av[ks];
    int kk = ks * 32 + q * 8;
#pragma unroll
    for (int t5 = 0; t5 < 5; ++t5) {
      half8 b = *(const half8*)&smem[(t5 * 16 + m) * 136 + kk];
      acc[t5] = __builtin_amdgcn_mfma_f32_16x16x32_f16(a, b, acc[t5], 0, 0, 0);
    }
  }
  __syncthreads();  // sW reads done -> alias
  unsigned short* sTp = smem;               // [64][72] halves (p rows, 16B-aligned rows)
  float* sTo = (float*)(smem + 4608);       // [64][44] floats (out rows)
  // zero p-pad cols 40..63 (words 20..31 per row)
  {
    unsigned int* zp = (unsigned int*)sTp;
    for (int idx = t; idx < 768; idx += 256) {
      int r = idx / 12, wc = 20 + idx % 12;
      zp[r * 36 + wc] = 0u;
    }
  }
  // transpose writes
  float on4[4];
#pragma unroll
  for (int i = 0; i < 4; ++i) {
    int row = row0 + w * 16 + q * 4 + i;
    on4[i] = out_norm[min(row, N_NODES - 1)];
  }
#pragma unroll
  for (int t5 = 0; t5 < 5; ++t5) {
    int c = t5 * 16 + m;
#pragma unroll
    for (int i = 0; i < 4; ++i) {
      int r = w * 16 + q * 4 + i;
      if (c < 40) {
        sTp[r * 72 + c] = __half_as_ushort(__float2half_rn(on4[i] * acc[t5][i]));
      } else {
        sTo[r * 44 + (c - 40)] = acc[t5][i] + b2[c - 40];
      }
    }
  }
  __syncthreads();
  // coalesced stores: p rows = 8 uint4 (cols 0..63 incl. zero pad)
#pragma unroll
  for (int it = 0; it < 2; ++it) {
    int idx = it * 256 + t;               // 0..511
    int r = idx >> 3, gg = idx & 7;
    int row = row0 + r;
    if (row < N_NODES)
      *(uint4*)((unsigned short*)p + (size_t)row * 64 + gg * 8) = *(const uint4*)&sTp[r * 72 + gg * 8];
  }
  // out rows = 10 float4
  for (int it = 0; it < 3; ++it) {
    int idx = it * 256 + t;               // 0..767, guard 640
    if (idx < 640) {
      int r = idx / 10, gg = idx % 10;
      int row = row0 + r;
      if (row < N_NODES)
        *(float4*)(out + (size_t)row * 40 + gg * 4) = *(const float4*)&sTo[r * 44 + gg * 4];
    }
  }
}

// ---------------- layer-2 aggregation (octet uint4 gather on 128B padded rows):
// out[d] += in_norm[d] * sum_e p[src]. 8 lanes x 16B = one row; 8 edges per instruction.
__global__ void k_agg64h(const __half* __restrict__ p, const int* __restrict__ col,
                         const int* __restrict__ row_start,
                         const float* __restrict__ in_norm,
                         float* __restrict__ out) {
  int wave = threadIdx.x >> 6, lane = threadIdx.x & 63;
  int node = blockIdx.x * 4 + wave;
  if (node >= N_NODES) return;
  int oct = lane >> 3;  // 8 octets, each walks edges s0+oct, s0+oct+8, ...
  int sub = lane & 7;   // 8 lanes x 16B cover the 128B row
  int s0 = row_start[node], s1 = row_start[node + 1];
  const uint4* pp = (const uint4*)p;  // row = 8 uint4
  float a[8];
#pragma unroll
  for (int j = 0; j < 8; ++j) a[j] = 0.f;
  int e = s0 + oct;
  for (; e + 8 < s1; e += 16) {
    int c0 = col[e];
    int c1 = col[e + 8];
    uint4 u0 = pp[(size_t)c0 * 8 + sub];
    uint4 u1 = pp[(size_t)c1 * 8 + sub];
    const __half2* h0 = (const __half2*)&u0;
    const __half2* h1 = (const __half2*)&u1;
#pragma unroll
    for (int j = 0; j < 4; ++j) {
      float2 f0 = __half22float2(h0[j]);
      float2 f1 = __half22float2(h1[j]);
      a[2 * j] += f0.x + f1.x;
      a[2 * j + 1] += f0.y + f1.y;
    }
  }
  if (e < s1) {
    uint4 u = pp[(size_t)col[e] * 8 + sub];
    const __half2* h0 = (const __half2*)&u;
#pragma unroll
    for (int j = 0; j < 4; ++j) {
      float2 f = __half22float2(h0[j]);
      a[2 * j] += f.x;
      a[2 * j + 1] += f.y;
    }
  }
  // combine octets (shfl strides 8/16/32 preserve sub)
#pragma unroll
  for (int j = 0; j < 8; ++j) {
    a[j] += __shfl_xor(a[j], 8);
    a[j] += __shfl_xor(a[j], 16);
    a[j] += __shfl_xor(a[j], 32);
  }
  if (oct == 0 && sub < 5) {  // cols [sub*8, sub*8+8) < 40
    float sc = in_norm[node];
    float4* op = (float4*)(out + (size_t)node * 40 + (size_t)sub * 8);
    float4 v0 = op[0], v1 = op[1];
    v0.x += sc * a[0]; v0.y += sc * a[1]; v0.z += sc * a[2]; v0.w += sc * a[3];
    v1.x += sc * a[4]; v1.y += sc * a[5]; v1.z += sc * a[6]; v1.w += sc * a[7];
    op[0] = v0; op[1] = v1;
  }
}

extern "C" void kernel_launch(void* const* d_in, const int* in_sizes, int n_in,
                              void* d_out, int out_size, void* d_ws, size_t ws_size,
                              hipStream_t stream) {
  const float* feat = (const float*)d_in[0];
  const int* src = (const int*)d_in[1];
  const int* dst = (const int*)d_in[2];
  const float* w0 = (const float*)d_in[3];
  const float* w1 = (const float*)d_in[4];
  const float* w2 = (const float*)d_in[5];
  const float* b2 = (const float*)d_in[6];
  const float* l0 = (const float*)d_in[7];
  const float* l1 = (const float*)d_in[8];
  const float* l2 = (const float*)d_in[9];
  const float* g0 = (const float*)d_in[10];
  const float* beta0 = (const float*)d_in[11];
  const float* g1 = (const float*)d_in[12];
  const float* beta1 = (const float*)d_in[13];
  float* out = (float*)d_out;

  char* ws = (char*)d_ws;
  size_t off = 0;
  auto alloc = [&](size_t bytes) {
    void* ptr = ws + off;
    off = (off + bytes + 255) & ~(size_t)255;
    return ptr;
  };
  unsigned short* A16 = (unsigned short*)alloc(2 * (size_t)N_NODES * 128);  // agg out / p (64-stride)
  float* B = (float*)alloc(sizeof(float) * (size_t)N_NODES * 128);          // Hparts (prep) / P0
  unsigned short* F = (unsigned short*)alloc(2 * (size_t)N_NODES * 128);    // feat fp16 / P1
  int* degd = (int*)alloc(sizeof(int) * N_NODES);
  int* row_start = (int*)alloc(sizeof(int) * (N_NODES + 1));
  int* colb = (int*)alloc(sizeof(int) * N_EDGES);
  float* out_norm = (float*)alloc(sizeof(float) * N_NODES);
  float* in_norm = (float*)alloc(sizeof(float) * N_NODES);
  int* bsum = (int*)alloc(sizeof(int) * 512);
  float* stats0 = (float*)alloc(sizeof(float) * 256);
  float* stats1 = (float*)alloc(sizeof(float) * 256);
  unsigned short* W16 = (unsigned short*)alloc(2 * (size_t)75776);          // fp16 weights
  int gb2 = (N_NODES + 127) / 128;  // 782 (BM=128 gemm blocks)
  int nstat = gb2 * 8;              // per-wave stats rows = 6256
  float* pstats = (float*)alloc(sizeof(float) * (size_t)nstat * 256);      // BN partials
  int gb64 = (N_NODES + 63) / 64;   // 1563 (gemm2 blocks)

  // Two Hpart tables (16.8 MB each) alias B (51.2 MB); consumed before P0's first write.
  unsigned int* Hs = (unsigned int*)B;            // src histogram
  unsigned int* Hd = Hs + (size_t)HCH * HRG * HWORDS;  // dst histogram (scanned -> bases)
  unsigned short* P0 = (unsigned short*)B;        // layer-0 pre-BN gemm out
  unsigned short* P1 = F;                         // layer-1 pre-BN gemm out (F dead by then)

  int nb = (N_NODES + 255) / 256;  // 391
  int hb = HCH * HRG;              // 256

  k_w2h<<<74, 256, 0, stream>>>(w0, l0, w1, l1, w2, l2, W16);

  k_hist_part<<<hb, 256, 0, stream>>>(src, Hs);
  k_hist_part<<<hb, 256, 0, stream>>>(dst, Hd);
  k_hist_scan2<<<nb, 256, 0, stream>>>((const unsigned short*)Hs, (unsigned short*)Hd,
                                       degd, out_norm, in_norm, bsum);
  k_scan2<<<1, 512, 0, stream>>>(bsum, nb);
  k_scan3<<<nb, 256, 0, stream>>>(degd, bsum, row_start);
  k_build<<<hb, 256, 0, stream>>>(src, dst, (const unsigned short*)Hd, row_start, colb);

  int ab = (N_NODES + 3) / 4;   // wave per node
  int fb = (N_NODES * 32 + 255) / 256;

  // layer 0: P0 = agg(feat)@w0^T + feat@l0^T   (pre-BN; stats accumulated)
  k_feat2h<<<fb, 256, 0, stream>>>(feat, F);
  k_agg128h<0><<<ab, 256, 0, stream>>>(F, colb, row_start, out_norm, in_norm,
                                       nullptr, nullptr, nullptr, A16);
  k_gemm_dual16<0><<<gb2, 512, 0, stream>>>(A16, F, nullptr, nullptr, nullptr,
                                            W16, P0, pstats);
  hipMemsetAsync(stats0, 0, sizeof(float) * 256, stream);
  k_stats_red<<<32, 256, 0, stream>>>(pstats, stats0, nstat);

  // layer 1: h1 = relu(bn(P0)) folded into consumers; P1 = agg(h1)@w1^T + h1@l1^T
  k_agg128h<1><<<ab, 256, 0, stream>>>(P0, colb, row_start, out_norm, in_norm,
                                       stats0, g0, beta0, A16);
  k_gemm_dual16<1><<<gb2, 512, 0, stream>>>(A16, P0, stats0, g0, beta0,
                                            W16 + 32768, P1, pstats);
  hipMemsetAsync(stats1, 0, sizeof(float) * 256, stream);
  k_stats_red<<<32, 256, 0, stream>>>(pstats, stats1, nstat);

  // layer 2: h2 = relu(bn(P1)) folded; out = in_norm*agg(fp16(out_norm*(h2@w2^T))) + b2 + h2@l2^T
  __half* p = (__half*)A16;  // A16 dead after layer-1 gemm; p is [N][64] fp16
  k_gemm2_16<<<gb64, 256, 0, stream>>>(P1, stats1, g1, beta1, W16 + 65536, b2, out_norm, p, out);
  k_agg64h<<<ab, 256, 0, stream>>>(p, colb, row_start, in_norm, out);
}

// Round 11
// 479.474 us; speedup vs baseline: 1.1663x; 1.1663x over previous
//
#include <hip/hip_runtime.h>
#include <hip/hip_fp16.h>
#include <cstdint>
#include <cstddef>

#define N_NODES 100000
#define N_EDGES 1600000
#define EPS 1e-5f

typedef _Float16 half8 __attribute__((ext_vector_type(8)));
typedef float floatx4 __attribute__((ext_vector_type(4)));

// LDS-binned histogram: ushort counters packed 2/uint (per-chunk count <= 25000 < 65536).
#define HCH 64                   // edge chunks
#define HRG 4                    // bin ranges
#define HBINS 32768              // ushort bins per range
#define HWORDS (HBINS / 2)       // 16384 uints = 64 KB LDS
#define HCHUNK (N_EDGES / HCH)   // 25000 edges per chunk
#define HCHUNK4 (HCHUNK / 4)     // 6250 int4 per chunk

// ---------------- graph prep (no device-scope atomics) ----------------
__global__ void k_hist_part(const int* __restrict__ keys, unsigned int* __restrict__ Hpart) {
  __shared__ unsigned int bins[HWORDS];
  int c = blockIdx.x % HCH, r = blockIdx.x / HCH;
  int base = r * HBINS;
  for (int i = threadIdx.x; i < HWORDS; i += 256) bins[i] = 0;
  __syncthreads();
  const int4* k4 = (const int4*)(keys + c * HCHUNK);
  for (int i = threadIdx.x; i < HCHUNK4; i += 256) {
    int4 k = k4[i];
    int a;
    a = k.x - base; if ((unsigned)a < (unsigned)HBINS) atomicAdd(&bins[a >> 1], 1u << ((a & 1) * 16));
    a = k.y - base; if ((unsigned)a < (unsigned)HBINS) atomicAdd(&bins[a >> 1], 1u << ((a & 1) * 16));
    a = k.z - base; if ((unsigned)a < (unsigned)HBINS) atomicAdd(&bins[a >> 1], 1u << ((a & 1) * 16));
    a = k.w - base; if ((unsigned)a < (unsigned)HBINS) atomicAdd(&bins[a >> 1], 1u << ((a & 1) * 16));
  }
  __syncthreads();
  unsigned int* outp = Hpart + ((size_t)blockIdx.x << 14);
  for (int i = threadIdx.x; i < HWORDS; i += 256) outp[i] = bins[i];
}

// Fused: src-histogram sum (-> out_norm) + dst-histogram exclusive scan (-> per-chunk
// bases, degd, in_norm) + per-256-node block sum for row_start scan.
__global__ void k_hist_scan2(const unsigned short* __restrict__ Hs,
                             unsigned short* __restrict__ Hd,
                             int* __restrict__ degd, float* __restrict__ out_norm,
                             float* __restrict__ in_norm, int* __restrict__ bsum) {
  __shared__ int sred[256];
  int t = threadIdx.x;
  int b = blockIdx.x * 256 + t;
  int total = 0;
  if (b < N_NODES) {
    int r = b >> 15, lo = b & (HBINS - 1);
    const unsigned short* ps = Hs + ((size_t)(r * HCH) << 15) + lo;
    unsigned int ds = 0;
#pragma unroll 8
    for (int c = 0; c < HCH; ++c) ds += ps[(size_t)c << 15];
    unsigned short* pd = Hd + ((size_t)(r * HCH) << 15) + lo;
    unsigned int tt = 0;
#pragma unroll 8
    for (int c = 0; c < HCH; ++c) {
      unsigned int v = pd[(size_t)c << 15];
      pd[(size_t)c << 15] = (unsigned short)tt;
      tt += v;
    }
    total = (int)tt;
    degd[b] = total;
    out_norm[b] = rsqrtf((float)max((int)ds, 1));
    in_norm[b] = rsqrtf((float)max(total, 1));
  }
  sred[t] = total;
  __syncthreads();
  for (int off = 128; off > 0; off >>= 1) {
    if (t < off) sred[t] += sred[t + off];
    __syncthreads();
  }
  if (t == 0) bsum[blockIdx.x] = sred[0];
}

__global__ void k_build(const int* __restrict__ src, const int* __restrict__ dst,
                        const unsigned short* __restrict__ Hbase,
                        const int* __restrict__ row_start, int* __restrict__ col) {
  __shared__ unsigned int cur[HWORDS];
  int c = blockIdx.x % HCH, r = blockIdx.x / HCH;
  int base = r * HBINS;
  for (int i = threadIdx.x; i < HWORDS; i += 256) cur[i] = 0;
  __syncthreads();
  const unsigned short* hb = Hbase + ((size_t)blockIdx.x << 15);
  const int4* d4 = (const int4*)(dst + c * HCHUNK);
  const int4* s4 = (const int4*)(src + c * HCHUNK);
  for (int i = threadIdx.x; i < HCHUNK4; i += 256) {
    int4 d = d4[i];
    int4 s = s4[i];
    int a;
    a = d.x - base;
    if ((unsigned)a < (unsigned)HBINS) {
      unsigned old = atomicAdd(&cur[a >> 1], 1u << ((a & 1) * 16));
      unsigned lr = (old >> ((a & 1) * 16)) & 0xffffu;
      col[row_start[d.x] + hb[a] + lr] = s.x;
    }
    a = d.y - base;
    if ((unsigned)a < (unsigned)HBINS) {
      unsigned old = atomicAdd(&cur[a >> 1], 1u << ((a & 1) * 16));
      unsigned lr = (old >> ((a & 1) * 16)) & 0xffffu;
      col[row_start[d.y] + hb[a] + lr] = s.y;
    }
    a = d.z - base;
    if ((unsigned)a < (unsigned)HBINS) {
      unsigned old = atomicAdd(&cur[a >> 1], 1u << ((a & 1) * 16));
      unsigned lr = (old >> ((a & 1) * 16)) & 0xffffu;
      col[row_start[d.z] + hb[a] + lr] = s.z;
    }
    a = d.w - base;
    if ((unsigned)a < (unsigned)HBINS) {
      unsigned old = atomicAdd(&cur[a >> 1], 1u << ((a & 1) * 16));
      unsigned lr = (old >> ((a & 1) * 16)) & 0xffffu;
      col[row_start[d.w] + hb[a] + lr] = s.w;
    }
  }
}

__global__ void k_scan2(int* bsum, int nb) {
  __shared__ int s[512];
  int t = threadIdx.x;
  int v = (t < nb) ? bsum[t] : 0;
  s[t] = v;
  __syncthreads();
  for (int off = 1; off < 512; off <<= 1) {
    int x = (t >= off) ? s[t - off] : 0;
    __syncthreads();
    s[t] += x;
    __syncthreads();
  }
  if (t < nb) bsum[t] = s[t] - v;  // exclusive
}

__global__ void k_scan3(const int* __restrict__ degd, const int* __restrict__ bsum,
                        int* row_start) {
  __shared__ int s[256];
  int t = threadIdx.x;
  int i = blockIdx.x * 256 + t;
  int v = (i < N_NODES) ? degd[i] : 0;
  s[t] = v;
  __syncthreads();
  for (int off = 1; off < 256; off <<= 1) {
    int x = (t >= off) ? s[t - off] : 0;
    __syncthreads();
    s[t] += x;
    __syncthreads();
  }
  if (i < N_NODES) row_start[i] = bsum[blockIdx.x] + s[t] - v;
  if (i == 0) row_start[N_NODES] = N_EDGES;
}

// ---------------- weights -> fp16, once per launch ----------------
// Layout (halves): w0@0, l0@16384, w1@32768, l1@49152, w2@65536, l2@70656 (total 75776)
__global__ void k_w2h(const float* __restrict__ w0, const float* __restrict__ l0,
                      const float* __restrict__ w1, const float* __restrict__ l1,
                      const float* __restrict__ w2, const float* __restrict__ l2,
                      unsigned short* __restrict__ W) {
  int i = blockIdx.x * 256 + threadIdx.x;  // float4 index
  if (i >= 18944) return;
  int h = i * 4;
  const float* src; int off;
  if (h < 16384)      { src = w0; off = h; }
  else if (h < 32768) { src = l0; off = h - 16384; }
  else if (h < 49152) { src = w1; off = h - 32768; }
  else if (h < 65536) { src = l1; off = h - 49152; }
  else if (h < 70656) { src = w2; off = h - 65536; }
  else                { src = l2; off = h - 70656; }
  float4 v = *(const float4*)(src + off);
  ushort4 o;
  o.x = __half_as_ushort(__float2half_rn(v.x));
  o.y = __half_as_ushort(__float2half_rn(v.y));
  o.z = __half_as_ushort(__float2half_rn(v.z));
  o.w = __half_as_ushort(__float2half_rn(v.w));
  ((ushort4*)W)[i] = o;
}

// ---------------- feat -> fp16 table (unscaled) ----
__global__ void k_feat2h(const float* __restrict__ feat, unsigned short* __restrict__ F) {
  int i = blockIdx.x * 256 + threadIdx.x;  // float4 index
  if (i >= N_NODES * 32) return;
  float4 v = ((const float4*)feat)[i];
  ushort4 u;
  u.x = __half_as_ushort(__float2half_rn(v.x));
  u.y = __half_as_ushort(__float2half_rn(v.y));
  u.z = __half_as_ushort(__float2half_rn(v.z));
  u.w = __half_as_ushort(__float2half_rn(v.w));
  ((ushort4*)F)[i] = u;
}

// ---------------- aggregation: quarter-wave gather (16 lanes x uint4 = one 256B row).
// out[d] = in_norm[d] * sum_e out_norm[src] * act(X[src]); act = fp32 BN+ReLU (BN=1) or id.
// BN machinery fully scoped under if constexpr: BN=0 pays zero LDS / zero extra VGPR.
template<int BN>
__global__ void k_agg128h(const unsigned short* __restrict__ X, const int* __restrict__ col,
                          const int* __restrict__ row_start,
                          const float* __restrict__ out_norm,
                          const float* __restrict__ in_norm,
                          const float* __restrict__ stats,
                          const float* __restrict__ g, const float* __restrict__ bb,
                          unsigned short* __restrict__ out16) {
  int t = threadIdx.x;
  int lane = t & 63;
  int sub = lane & 15;  // 16 lanes x 16B cover the 256B row
  float scR[8], shR[8];
  if constexpr (BN) {
    __shared__ float scA[128], shA[128];
    if (t < 128) {
      const float inv = 1.f / (float)N_NODES;
      float mu = stats[t] * inv;
      float var = stats[128 + t] * inv - mu * mu;
      float s = rsqrtf(var + EPS) * g[t];
      scA[t] = s;
      shA[t] = bb[t] - mu * s;
    }
    __syncthreads();
#pragma unroll
    for (int j = 0; j < 8; ++j) { scR[j] = scA[sub * 8 + j]; shR[j] = shA[sub * 8 + j]; }
  }
  int wave = t >> 6;
  int node = blockIdx.x * 4 + wave;
  if (node >= N_NODES) return;
  int q = lane >> 4;    // quarter 0..3 — each quarter walks edges s0+q, s0+q+4, ...
  int s0 = row_start[node], s1 = row_start[node + 1];
  const uint4* hp = (const uint4*)X;  // row = 16 uint4
  float a[8];
#pragma unroll
  for (int j = 0; j < 8; ++j) a[j] = 0.f;
  int e = s0 + q;
  for (; e + 4 < s1; e += 8) {
    int c0 = col[e];
    int c1 = col[e + 4];
    float on0 = out_norm[c0];
    float on1 = out_norm[c1];
    uint4 u0 = hp[(size_t)c0 * 16 + sub];
    uint4 u1 = hp[(size_t)c1 * 16 + sub];
    const __half2* h0 = (const __half2*)&u0;
    const __half2* h1 = (const __half2*)&u1;
#pragma unroll
    for (int j = 0; j < 4; ++j) {
      float2 f0 = __half22float2(h0[j]);
      float2 f1 = __half22float2(h1[j]);
      if constexpr (BN) {
        f0.x = fmaxf(f0.x * scR[2 * j] + shR[2 * j], 0.f);
        f0.y = fmaxf(f0.y * scR[2 * j + 1] + shR[2 * j + 1], 0.f);
        f1.x = fmaxf(f1.x * scR[2 * j] + shR[2 * j], 0.f);
        f1.y = fmaxf(f1.y * scR[2 * j + 1] + shR[2 * j + 1], 0.f);
      }
      a[2 * j] += on0 * f0.x + on1 * f1.x;
      a[2 * j + 1] += on0 * f0.y + on1 * f1.y;
    }
  }
  if (e < s1) {
    int c = col[e];
    float on = out_norm[c];
    uint4 u = hp[(size_t)c * 16 + sub];
    const __half2* h0 = (const __half2*)&u;
#pragma unroll
    for (int j = 0; j < 4; ++j) {
      float2 f = __half22float2(h0[j]);
      if constexpr (BN) {
        f.x = fmaxf(f.x * scR[2 * j] + shR[2 * j], 0.f);
        f.y = fmaxf(f.y * scR[2 * j + 1] + shR[2 * j + 1], 0.f);
      }
      a[2 * j] += on * f.x;
      a[2 * j + 1] += on * f.y;
    }
  }
  // combine quarters (same sub -> same row components)
#pragma unroll
  for (int j = 0; j < 8; ++j) {
    a[j] += __shfl_xor(a[j], 16);
    a[j] += __shfl_xor(a[j], 32);
  }
  if (q == 0) {
    float sc = in_norm[node];
    __half2 o[4];
#pragma unroll
    for (int j = 0; j < 4; ++j)
      o[j] = __float22half2_rn(make_float2(a[2 * j] * sc, a[2 * j + 1] * sc));
    ((uint4*)out16)[(size_t)node * 16 + sub] = *(const uint4*)o;
  }
}

// ---------------- MFMA dual GEMM + fused BN stats (r7 proven config: BM=64, 256 thr).
// Phase 0: A = Xa (aggregated, final). Phase 1: A = act(Xh) with act = BN+ReLU if BN.
// Direct-global A loads; weights LDS-staged; LDS-transpose coalesced epilogue.
template<int BN>
__launch_bounds__(256)
__global__ void k_gemm_dual16(const unsigned short* __restrict__ Xa,
                              const unsigned short* __restrict__ Xh,
                              const float* __restrict__ stats,
                              const float* __restrict__ g, const float* __restrict__ bb,
                              const unsigned short* __restrict__ W16,  // [2][128][128] fp16
                              unsigned short* __restrict__ Out16, float* __restrict__ pstats) {
  __shared__ __align__(16) unsigned short smem[128 * 136];  // sW compute / sT+stats epilogue
  __shared__ float scA[128], shA[128];
  int t = threadIdx.x;
  int row0 = blockIdx.x * 64;
  int w = t >> 6, lane = t & 63;
  int q = lane >> 4, m = lane & 15;
  if (BN && t < 128) {
    const float inv = 1.f / (float)N_NODES;
    float mu = stats[t] * inv;
    float var = stats[128 + t] * inv - mu * mu;
    float s = rsqrtf(var + EPS) * g[t];
    scA[t] = s;
    shA[t] = bb[t] - mu * s;
  }
  size_t arow = (size_t)min(row0 + w * 16 + m, N_NODES - 1);
  floatx4 acc[8];
#pragma unroll
  for (int i = 0; i < 8; ++i) acc[i] = (floatx4){0.f, 0.f, 0.f, 0.f};

  for (int phase = 0; phase < 2; ++phase) {
    const unsigned short* Xg = phase ? Xh : Xa;
    const uint4* xr = (const uint4*)Xg + arow * 16 + q;   // + ks*4
    uint4 av[4];
    av[0] = xr[0]; av[1] = xr[4]; av[2] = xr[8]; av[3] = xr[12];  // in flight over staging
    __syncthreads();  // phase 1: previous sW reads done; also orders scA writes
    {
      const uint4* wsrc = (const uint4*)(W16 + ((size_t)phase << 14));
#pragma unroll
      for (int it = 0; it < 8; ++it) {
        int idx = it * 256 + t;          // 0..2047, fully coalesced
        *(uint4*)&smem[(idx >> 4) * 136 + (idx & 15) * 8] = wsrc[idx];
      }
    }
    if (BN && phase == 1) {
#pragma unroll
      for (int ks = 0; ks < 4; ++ks) {
        int kk = ks * 32 + q * 8;
        __half2* hh = (__half2*)&av[ks];
#pragma unroll
        for (int j = 0; j < 4; ++j) {
          float2 f = __half22float2(hh[j]);
          f.x = fmaxf(f.x * scA[kk + 2 * j] + shA[kk + 2 * j], 0.f);
          f.y = fmaxf(f.y * scA[kk + 2 * j + 1] + shA[kk + 2 * j + 1], 0.f);
          hh[j] = __float22half2_rn(f);
        }
      }
    }
    __syncthreads();
#pragma unroll
    for (int ks = 0; ks < 4; ++ks) {
      half8 a = *(half8*)&av[ks];
      int kk = ks * 32 + q * 8;
#pragma unroll
      for (int t8 = 0; t8 < 8; ++t8) {
        half8 b = *(const half8*)&smem[(t8 * 16 + m) * 136 + kk];
        acc[t8] = __builtin_amdgcn_mfma_f32_16x16x32_f16(a, b, acc[t8], 0, 0, 0);
      }
    }
  }
  // BN partial stats (register + shfl)
  float ps[8], pq[8];
#pragma unroll
  for (int t8 = 0; t8 < 8; ++t8) {
    float s = 0.f, sq = 0.f;
#pragma unroll
    for (int i = 0; i < 4; ++i) {
      int row = row0 + w * 16 + q * 4 + i;
      if (row < N_NODES) {
        float v = acc[t8][i];
        s += v; sq += v * v;
      }
    }
    s += __shfl_xor(s, 16);
    s += __shfl_xor(s, 32);
    sq += __shfl_xor(sq, 16);
    sq += __shfl_xor(sq, 32);
    ps[t8] = s; pq[t8] = sq;
  }
  __syncthreads();  // all MFMA reads of sW done -> safe to alias
  // transpose epilogue: sT[64][136] halves + stats region after
  unsigned short* sT = smem;
  float* pSum = (float*)(smem + 8704);   // [4][128]
  float* pSq = pSum + 512;               // [4][128]
#pragma unroll
  for (int t8 = 0; t8 < 8; ++t8) {
    int c = t8 * 16 + m;
#pragma unroll
    for (int i = 0; i < 4; ++i) {
      int r = w * 16 + q * 4 + i;
      sT[r * 136 + c] = __half_as_ushort(__float2half_rn(acc[t8][i]));
    }
    if (q == 0) {
      pSum[w * 128 + c] = ps[t8];
      pSq[w * 128 + c] = pq[t8];
    }
  }
  __syncthreads();
  // coalesced uint4 stores (4 per thread)
#pragma unroll
  for (int it = 0; it < 4; ++it) {
    int idx = it * 256 + t;
    int r = idx >> 4, gg = idx & 15;
    int row = row0 + r;
    if (row < N_NODES)
      *(uint4*)&Out16[(size_t)row * 128 + gg * 8] = *(const uint4*)&sT[r * 136 + gg * 8];
  }
  if (t < 128) {
    float s = (pSum[t] + pSum[128 + t]) + (pSum[256 + t] + pSum[384 + t]);
    float sq = (pSq[t] + pSq[128 + t]) + (pSq[256 + t] + pSq[384 + t]);
    pstats[(size_t)blockIdx.x * 256 + t] = s;          // non-atomic per-block partials
    pstats[(size_t)blockIdx.x * 256 + 128 + t] = sq;
  }
}

// ---------------- stats reduction: [nblk][256] -> [256]
__global__ void k_stats_red(const float* __restrict__ pstats, float* __restrict__ stats,
                            int nblk) {
  int t = threadIdx.x;
  float s = 0.f;
  for (int b = blockIdx.x; b < nblk; b += gridDim.x)
    s += pstats[(size_t)b * 256 + t];
  atomicAdd(&stats[t], s);  // 32 blocks x 256 = 8K atomics total, negligible
}

// ---------------- MFMA layer-2 GEMM on h2 = BN+ReLU(P1) (folded):
//   p = fp16(out_norm*(h2@w2^T)) [stride 64, zero-padded]; out = h2@l2^T + b2.
__launch_bounds__(256)
__global__ void k_gemm2_16(const unsigned short* __restrict__ X,  // P1 pre-BN
                           const float* __restrict__ stats,
                           const float* __restrict__ g, const float* __restrict__ bb,
                           const unsigned short* __restrict__ W80,  // [80][128] fp16: w2 then l2
                           const float* __restrict__ b2,
                           const float* __restrict__ out_norm,
                           __half* __restrict__ p, float* __restrict__ out) {
  __shared__ __align__(16) unsigned short smem[80 * 136];  // sW compute / sTp+sTo epilogue
  __shared__ float scA[128], shA[128];
  int t = threadIdx.x;
  int row0 = blockIdx.x * 64;
  int w = t >> 6, lane = t & 63;
  int q = lane >> 4, m = lane & 15;
  if (t < 128) {
    const float inv = 1.f / (float)N_NODES;
    float mu = stats[t] * inv;
    float var = stats[128 + t] * inv - mu * mu;
    float s = rsqrtf(var + EPS) * g[t];
    scA[t] = s;
    shA[t] = bb[t] - mu * s;
  }
  size_t arow = (size_t)min(row0 + w * 16 + m, N_NODES - 1);
  const uint4* xr = (const uint4*)X + arow * 16 + q;
  uint4 av[4];
  av[0] = xr[0]; av[1] = xr[4]; av[2] = xr[8]; av[3] = xr[12];
  {
    const uint4* wsrc = (const uint4*)W80;  // 80*16 = 1280 uint4
#pragma unroll
    for (int it = 0; it < 5; ++it) {
      int idx = it * 256 + t;
      *(uint4*)&smem[(idx >> 4) * 136 + (idx & 15) * 8] = wsrc[idx];
    }
  }
  __syncthreads();
  // fold BN+ReLU into A-fragments
#pragma unroll
  for (int ks = 0; ks < 4; ++ks) {
    int kk = ks * 32 + q * 8;
    __half2* hh = (__half2*)&av[ks];
#pragma unroll
    for (int j = 0; j < 4; ++j) {
      float2 f = __half22float2(hh[j]);
      f.x = fmaxf(f.x * scA[kk + 2 * j] + shA[kk + 2 * j], 0.f);
      f.y = fmaxf(f.y * scA[kk + 2 * j + 1] + shA[kk + 2 * j + 1], 0.f);
      hh[j] = __float22half2_rn(f);
    }
  }
  floatx4 acc[5];
#pragma unroll
  for (int i = 0; i < 5; ++i) acc[i] = (floatx4){0.f, 0.f, 0.f, 0.f};
#pragma unroll
  for (int ks = 0; ks < 4; ++ks) {
    half8 a = *(half8*)&av[ks];
    int kk = ks * 32 + q * 8;
#pragma unroll
    for (int t5 = 0; t5 < 5; ++t5) {
      half8 b = *(const half8*)&smem[(t5 * 16 + m) * 136 + kk];
      acc[t5] = __builtin_amdgcn_mfma_f32_16x16x32_f16(a, b, acc[t5], 0, 0, 0);
    }
  }
  __syncthreads();  // sW reads done -> alias
  unsigned short* sTp = smem;               // [64][72] halves (p rows, 16B-aligned rows)
  float* sTo = (float*)(smem + 4608);       // [64][44] floats (out rows)
  // zero p-pad cols 40..63 (words 20..31 per row)
  {
    unsigned int* zp = (unsigned int*)sTp;
    for (int idx = t; idx < 768; idx += 256) {
      int r = idx / 12, wc = 20 + idx % 12;
      zp[r * 36 + wc] = 0u;
    }
  }
  // transpose writes
  float on4[4];
#pragma unroll
  for (int i = 0; i < 4; ++i) {
    int row = row0 + w * 16 + q * 4 + i;
    on4[i] = out_norm[min(row, N_NODES - 1)];
  }
#pragma unroll
  for (int t5 = 0; t5 < 5; ++t5) {
    int c = t5 * 16 + m;
#pragma unroll
    for (int i = 0; i < 4; ++i) {
      int r = w * 16 + q * 4 + i;
      if (c < 40) {
        sTp[r * 72 + c] = __half_as_ushort(__float2half_rn(on4[i] * acc[t5][i]));
      } else {
        sTo[r * 44 + (c - 40)] = acc[t5][i] + b2[c - 40];
      }
    }
  }
  __syncthreads();
  // coalesced stores: p rows = 8 uint4 (cols 0..63 incl. zero pad)
#pragma unroll
  for (int it = 0; it < 2; ++it) {
    int idx = it * 256 + t;               // 0..511
    int r = idx >> 3, gg = idx & 7;
    int row = row0 + r;
    if (row < N_NODES)
      *(uint4*)((unsigned short*)p + (size_t)row * 64 + gg * 8) = *(const uint4*)&sTp[r * 72 + gg * 8];
  }
  // out rows = 10 float4
  for (int it = 0; it < 3; ++it) {
    int idx = it * 256 + t;               // 0..767, guard 640
    if (idx < 640) {
      int r = idx / 10, gg = idx % 10;
      int row = row0 + r;
      if (row < N_NODES)
        *(float4*)(out + (size_t)row * 40 + gg * 4) = *(const float4*)&sTo[r * 44 + gg * 4];
    }
  }
}

// ---------------- layer-2 aggregation (octet uint4 gather on 128B padded rows):
// out[d] += in_norm[d] * sum_e p[src]. 8 lanes x 16B = one row; 8 edges per instruction.
__global__ void k_agg64h(const __half* __restrict__ p, const int* __restrict__ col,
                         const int* __restrict__ row_start,
                         const float* __restrict__ in_norm,
                         float* __restrict__ out) {
  int wave = threadIdx.x >> 6, lane = threadIdx.x & 63;
  int node = blockIdx.x * 4 + wave;
  if (node >= N_NODES) return;
  int oct = lane >> 3;  // 8 octets, each walks edges s0+oct, s0+oct+8, ...
  int sub = lane & 7;   // 8 lanes x 16B cover the 128B row
  int s0 = row_start[node], s1 = row_start[node + 1];
  const uint4* pp = (const uint4*)p;  // row = 8 uint4
  float a[8];
#pragma unroll
  for (int j = 0; j < 8; ++j) a[j] = 0.f;
  int e = s0 + oct;
  for (; e + 8 < s1; e += 16) {
    int c0 = col[e];
    int c1 = col[e + 8];
    uint4 u0 = pp[(size_t)c0 * 8 + sub];
    uint4 u1 = pp[(size_t)c1 * 8 + sub];
    const __half2* h0 = (const __half2*)&u0;
    const __half2* h1 = (const __half2*)&u1;
#pragma unroll
    for (int j = 0; j < 4; ++j) {
      float2 f0 = __half22float2(h0[j]);
      float2 f1 = __half22float2(h1[j]);
      a[2 * j] += f0.x + f1.x;
      a[2 * j + 1] += f0.y + f1.y;
    }
  }
  if (e < s1) {
    uint4 u = pp[(size_t)col[e] * 8 + sub];
    const __half2* h0 = (const __half2*)&u;
#pragma unroll
    for (int j = 0; j < 4; ++j) {
      float2 f = __half22float2(h0[j]);
      a[2 * j] += f.x;
      a[2 * j + 1] += f.y;
    }
  }
  // combine octets (shfl strides 8/16/32 preserve sub)
#pragma unroll
  for (int j = 0; j < 8; ++j) {
    a[j] += __shfl_xor(a[j], 8);
    a[j] += __shfl_xor(a[j], 16);
    a[j] += __shfl_xor(a[j], 32);
  }
  if (oct == 0 && sub < 5) {  // cols [sub*8, sub*8+8) < 40
    float sc = in_norm[node];
    float4* op = (float4*)(out + (size_t)node * 40 + (size_t)sub * 8);
    float4 v0 = op[0], v1 = op[1];
    v0.x += sc * a[0]; v0.y += sc * a[1]; v0.z += sc * a[2]; v0.w += sc * a[3];
    v1.x += sc * a[4]; v1.y += sc * a[5]; v1.z += sc * a[6]; v1.w += sc * a[7];
    op[0] = v0; op[1] = v1;
  }
}

extern "C" void kernel_launch(void* const* d_in, const int* in_sizes, int n_in,
                              void* d_out, int out_size, void* d_ws, size_t ws_size,
                              hipStream_t stream) {
  const float* feat = (const float*)d_in[0];
  const int* src = (const int*)d_in[1];
  const int* dst = (const int*)d_in[2];
  const float* w0 = (const float*)d_in[3];
  const float* w1 = (const float*)d_in[4];
  const float* w2 = (const float*)d_in[5];
  const float* b2 = (const float*)d_in[6];
  const float* l0 = (const float*)d_in[7];
  const float* l1 = (const float*)d_in[8];
  const float* l2 = (const float*)d_in[9];
  const float* g0 = (const float*)d_in[10];
  const float* beta0 = (const float*)d_in[11];
  const float* g1 = (const float*)d_in[12];
  const float* beta1 = (const float*)d_in[13];
  float* out = (float*)d_out;

  char* ws = (char*)d_ws;
  size_t off = 0;
  auto alloc = [&](size_t bytes) {
    void* ptr = ws + off;
    off = (off + bytes + 255) & ~(size_t)255;
    return ptr;
  };
  unsigned short* A16 = (unsigned short*)alloc(2 * (size_t)N_NODES * 128);  // agg out / p (64-stride)
  float* B = (float*)alloc(sizeof(float) * (size_t)N_NODES * 128);          // Hparts (prep) / P0
  unsigned short* F = (unsigned short*)alloc(2 * (size_t)N_NODES * 128);    // feat fp16 / P1
  int* degd = (int*)alloc(sizeof(int) * N_NODES);
  int* row_start = (int*)alloc(sizeof(int) * (N_NODES + 1));
  int* colb = (int*)alloc(sizeof(int) * N_EDGES);
  float* out_norm = (float*)alloc(sizeof(float) * N_NODES);
  float* in_norm = (float*)alloc(sizeof(float) * N_NODES);
  int* bsum = (int*)alloc(sizeof(int) * 512);
  float* stats0 = (float*)alloc(sizeof(float) * 256);
  float* stats1 = (float*)alloc(sizeof(float) * 256);
  unsigned short* W16 = (unsigned short*)alloc(2 * (size_t)75776);          // fp16 weights
  int gb = (N_NODES + 63) / 64;  // 1563
  float* pstats = (float*)alloc(sizeof(float) * (size_t)gb * 256);          // BN partials

  // Two Hpart tables (16.8 MB each) alias B (51.2 MB); consumed before P0's first write.
  unsigned int* Hs = (unsigned int*)B;            // src histogram
  unsigned int* Hd = Hs + (size_t)HCH * HRG * HWORDS;  // dst histogram (scanned -> bases)
  unsigned short* P0 = (unsigned short*)B;        // layer-0 pre-BN gemm out
  unsigned short* P1 = F;                         // layer-1 pre-BN gemm out (F dead by then)

  int nb = (N_NODES + 255) / 256;  // 391
  int hb = HCH * HRG;              // 256

  k_w2h<<<74, 256, 0, stream>>>(w0, l0, w1, l1, w2, l2, W16);

  k_hist_part<<<hb, 256, 0, stream>>>(src, Hs);
  k_hist_part<<<hb, 256, 0, stream>>>(dst, Hd);
  k_hist_scan2<<<nb, 256, 0, stream>>>((const unsigned short*)Hs, (unsigned short*)Hd,
                                       degd, out_norm, in_norm, bsum);
  k_scan2<<<1, 512, 0, stream>>>(bsum, nb);
  k_scan3<<<nb, 256, 0, stream>>>(degd, bsum, row_start);
  k_build<<<hb, 256, 0, stream>>>(src, dst, (const unsigned short*)Hd, row_start, colb);

  int ab = (N_NODES + 3) / 4;   // wave per node
  int fb = (N_NODES * 32 + 255) / 256;

  // layer 0: P0 = agg(feat)@w0^T + feat@l0^T   (pre-BN; stats accumulated)
  k_feat2h<<<fb, 256, 0, stream>>>(feat, F);
  k_agg128h<0><<<ab, 256, 0, stream>>>(F, colb, row_start, out_norm, in_norm,
                                       nullptr, nullptr, nullptr, A16);
  k_gemm_dual16<0><<<gb, 256, 0, stream>>>(A16, F, nullptr, nullptr, nullptr,
                                           W16, P0, pstats);
  hipMemsetAsync(stats0, 0, sizeof(float) * 256, stream);
  k_stats_red<<<32, 256, 0, stream>>>(pstats, stats0, gb);

  // layer 1: h1 = relu(bn(P0)) folded into consumers; P1 = agg(h1)@w1^T + h1@l1^T
  k_agg128h<1><<<ab, 256, 0, stream>>>(P0, colb, row_start, out_norm, in_norm,
                                       stats0, g0, beta0, A16);
  k_gemm_dual16<1><<<gb, 256, 0, stream>>>(A16, P0, stats0, g0, beta0,
                                           W16 + 32768, P1, pstats);
  hipMemsetAsync(stats1, 0, sizeof(float) * 256, stream);
  k_stats_red<<<32, 256, 0, stream>>>(pstats, stats1, gb);

  // layer 2: h2 = relu(bn(P1)) folded; out = in_norm*agg(fp16(out_norm*(h2@w2^T))) + b2 + h2@l2^T
  __half* p = (__half*)A16;  // A16 dead after layer-1 gemm; p is [N][64] fp16
  k_gemm2_16<<<gb, 256, 0, stream>>>(P1, stats1, g1, beta1, W16 + 65536, b2, out_norm, p, out);
  k_agg64h<<<ab, 256, 0, stream>>>(p, colb, row_start, in_norm, out);
}

// Round 12
// 463.217 us; speedup vs baseline: 1.2072x; 1.0351x over previous
//
#include <hip/hip_runtime.h>
#include <hip/hip_fp16.h>
#include <cstdint>
#include <cstddef>

#define N_NODES 100000
#define N_EDGES 1600000
#define EPS 1e-5f

typedef _Float16 half8 __attribute__((ext_vector_type(8)));
typedef float floatx4 __attribute__((ext_vector_type(4)));

// LDS-binned histogram: ushort counters packed 2/uint (per-chunk count <= 25000 < 65536).
#define HCH 64                   // edge chunks
#define HRG 4                    // bin ranges
#define HBINS 32768              // ushort bins per range
#define HWORDS (HBINS / 2)       // 16384 uints = 64 KB LDS
#define HCHUNK (N_EDGES / HCH)   // 25000 edges per chunk
#define HCHUNK4 (HCHUNK / 4)     // 6250 int4 per chunk

// ---------------- graph prep (no device-scope atomics) ----------------
// Both histograms in ONE launch (512 blocks): blockIdx>>8 selects src->Hs vs dst->Hd.
// 2 blocks/CU co-resident (128KB LDS) -> LDS-atomic latency interleaves across blocks.
__global__ void k_hist_both(const int* __restrict__ src, const int* __restrict__ dst,
                            unsigned int* __restrict__ Hs, unsigned int* __restrict__ Hd) {
  __shared__ unsigned int bins[HWORDS];
  int half = blockIdx.x >> 8;
  int bb = blockIdx.x & 255;
  const int* keys = half ? dst : src;
  unsigned int* Hpart = half ? Hd : Hs;
  int c = bb % HCH, r = bb / HCH;
  int base = r * HBINS;
  for (int i = threadIdx.x; i < HWORDS; i += 256) bins[i] = 0;
  __syncthreads();
  const int4* k4 = (const int4*)(keys + c * HCHUNK);
  for (int i = threadIdx.x; i < HCHUNK4; i += 256) {
    int4 k = k4[i];
    int a;
    a = k.x - base; if ((unsigned)a < (unsigned)HBINS) atomicAdd(&bins[a >> 1], 1u << ((a & 1) * 16));
    a = k.y - base; if ((unsigned)a < (unsigned)HBINS) atomicAdd(&bins[a >> 1], 1u << ((a & 1) * 16));
    a = k.z - base; if ((unsigned)a < (unsigned)HBINS) atomicAdd(&bins[a >> 1], 1u << ((a & 1) * 16));
    a = k.w - base; if ((unsigned)a < (unsigned)HBINS) atomicAdd(&bins[a >> 1], 1u << ((a & 1) * 16));
  }
  __syncthreads();
  unsigned int* outp = Hpart + ((size_t)bb << 14);
  for (int i = threadIdx.x; i < HWORDS; i += 256) outp[i] = bins[i];
}

// Fused: src-histogram sum (-> out_norm) + dst-histogram exclusive scan (-> per-chunk
// bases, degd, in_norm) + per-256-node block sum for row_start scan.
__global__ void k_hist_scan2(const unsigned short* __restrict__ Hs,
                             unsigned short* __restrict__ Hd,
                             int* __restrict__ degd, float* __restrict__ out_norm,
                             float* __restrict__ in_norm, int* __restrict__ bsum) {
  __shared__ int sred[256];
  int t = threadIdx.x;
  int b = blockIdx.x * 256 + t;
  int total = 0;
  if (b < N_NODES) {
    int r = b >> 15, lo = b & (HBINS - 1);
    const unsigned short* ps = Hs + ((size_t)(r * HCH) << 15) + lo;
    unsigned int ds = 0;
#pragma unroll 8
    for (int c = 0; c < HCH; ++c) ds += ps[(size_t)c << 15];
    unsigned short* pd = Hd + ((size_t)(r * HCH) << 15) + lo;
    unsigned int tt = 0;
#pragma unroll 8
    for (int c = 0; c < HCH; ++c) {
      unsigned int v = pd[(size_t)c << 15];
      pd[(size_t)c << 15] = (unsigned short)tt;
      tt += v;
    }
    total = (int)tt;
    degd[b] = total;
    out_norm[b] = rsqrtf((float)max((int)ds, 1));
    in_norm[b] = rsqrtf((float)max(total, 1));
  }
  sred[t] = total;
  __syncthreads();
  for (int off = 128; off > 0; off >>= 1) {
    if (t < off) sred[t] += sred[t + off];
    __syncthreads();
  }
  if (t == 0) bsum[blockIdx.x] = sred[0];
}

__global__ void k_build(const int* __restrict__ src, const int* __restrict__ dst,
                        const unsigned short* __restrict__ Hbase,
                        const int* __restrict__ row_start, int* __restrict__ col) {
  __shared__ unsigned int cur[HWORDS];
  int c = blockIdx.x % HCH, r = blockIdx.x / HCH;
  int base = r * HBINS;
  for (int i = threadIdx.x; i < HWORDS; i += 256) cur[i] = 0;
  __syncthreads();
  const unsigned short* hb = Hbase + ((size_t)blockIdx.x << 15);
  const int4* d4 = (const int4*)(dst + c * HCHUNK);
  const int4* s4 = (const int4*)(src + c * HCHUNK);
  for (int i = threadIdx.x; i < HCHUNK4; i += 256) {
    int4 d = d4[i];
    int4 s = s4[i];
    int a;
    a = d.x - base;
    if ((unsigned)a < (unsigned)HBINS) {
      unsigned old = atomicAdd(&cur[a >> 1], 1u << ((a & 1) * 16));
      unsigned lr = (old >> ((a & 1) * 16)) & 0xffffu;
      col[row_start[d.x] + hb[a] + lr] = s.x;
    }
    a = d.y - base;
    if ((unsigned)a < (unsigned)HBINS) {
      unsigned old = atomicAdd(&cur[a >> 1], 1u << ((a & 1) * 16));
      unsigned lr = (old >> ((a & 1) * 16)) & 0xffffu;
      col[row_start[d.y] + hb[a] + lr] = s.y;
    }
    a = d.z - base;
    if ((unsigned)a < (unsigned)HBINS) {
      unsigned old = atomicAdd(&cur[a >> 1], 1u << ((a & 1) * 16));
      unsigned lr = (old >> ((a & 1) * 16)) & 0xffffu;
      col[row_start[d.z] + hb[a] + lr] = s.z;
    }
    a = d.w - base;
    if ((unsigned)a < (unsigned)HBINS) {
      unsigned old = atomicAdd(&cur[a >> 1], 1u << ((a & 1) * 16));
      unsigned lr = (old >> ((a & 1) * 16)) & 0xffffu;
      col[row_start[d.w] + hb[a] + lr] = s.w;
    }
  }
}

__global__ void k_scan2(int* bsum, int nb) {
  __shared__ int s[512];
  int t = threadIdx.x;
  int v = (t < nb) ? bsum[t] : 0;
  s[t] = v;
  __syncthreads();
  for (int off = 1; off < 512; off <<= 1) {
    int x = (t >= off) ? s[t - off] : 0;
    __syncthreads();
    s[t] += x;
    __syncthreads();
  }
  if (t < nb) bsum[t] = s[t] - v;  // exclusive
}

__global__ void k_scan3(const int* __restrict__ degd, const int* __restrict__ bsum,
                        int* row_start) {
  __shared__ int s[256];
  int t = threadIdx.x;
  int i = blockIdx.x * 256 + t;
  int v = (i < N_NODES) ? degd[i] : 0;
  s[t] = v;
  __syncthreads();
  for (int off = 1; off < 256; off <<= 1) {
    int x = (t >= off) ? s[t - off] : 0;
    __syncthreads();
    s[t] += x;
    __syncthreads();
  }
  if (i < N_NODES) row_start[i] = bsum[blockIdx.x] + s[t] - v;
  if (i == 0) row_start[N_NODES] = N_EDGES;
}

// ---------------- weights -> fp16, once per launch ----------------
// Layout (halves): w0@0, l0@16384, w1@32768, l1@49152, w2@65536, l2@70656 (total 75776)
__global__ void k_w2h(const float* __restrict__ w0, const float* __restrict__ l0,
                      const float* __restrict__ w1, const float* __restrict__ l1,
                      const float* __restrict__ w2, const float* __restrict__ l2,
                      unsigned short* __restrict__ W) {
  int i = blockIdx.x * 256 + threadIdx.x;  // float4 index
  if (i >= 18944) return;
  int h = i * 4;
  const float* src; int off;
  if (h < 16384)      { src = w0; off = h; }
  else if (h < 32768) { src = l0; off = h - 16384; }
  else if (h < 49152) { src = w1; off = h - 32768; }
  else if (h < 65536) { src = l1; off = h - 49152; }
  else if (h < 70656) { src = w2; off = h - 65536; }
  else                { src = l2; off = h - 70656; }
  float4 v = *(const float4*)(src + off);
  ushort4 o;
  o.x = __half_as_ushort(__float2half_rn(v.x));
  o.y = __half_as_ushort(__float2half_rn(v.y));
  o.z = __half_as_ushort(__float2half_rn(v.z));
  o.w = __half_as_ushort(__float2half_rn(v.w));
  ((ushort4*)W)[i] = o;
}

// ---------------- feat -> fp16 table (unscaled) ----
__global__ void k_feat2h(const float* __restrict__ feat, unsigned short* __restrict__ F) {
  int i = blockIdx.x * 256 + threadIdx.x;  // float4 index
  if (i >= N_NODES * 32) return;
  float4 v = ((const float4*)feat)[i];
  ushort4 u;
  u.x = __half_as_ushort(__float2half_rn(v.x));
  u.y = __half_as_ushort(__float2half_rn(v.y));
  u.z = __half_as_ushort(__float2half_rn(v.z));
  u.w = __half_as_ushort(__float2half_rn(v.w));
  ((ushort4*)F)[i] = u;
}

// ---------------- aggregation: quarter-wave gather (16 lanes x uint4 = one 256B row).
// out[d] = in_norm[d] * sum_e out_norm[src] * act(X[src]); act = fp32 BN+ReLU (BN=1) or id.
// BN machinery fully scoped under if constexpr: BN=0 pays zero LDS / zero extra VGPR.
template<int BN>
__global__ void k_agg128h(const unsigned short* __restrict__ X, const int* __restrict__ col,
                          const int* __restrict__ row_start,
                          const float* __restrict__ out_norm,
                          const float* __restrict__ in_norm,
                          const float* __restrict__ stats,
                          const float* __restrict__ g, const float* __restrict__ bb,
                          unsigned short* __restrict__ out16) {
  int t = threadIdx.x;
  int lane = t & 63;
  int sub = lane & 15;  // 16 lanes x 16B cover the 256B row
  float scR[8], shR[8];
  if constexpr (BN) {
    __shared__ float scA[128], shA[128];
    if (t < 128) {
      const float inv = 1.f / (float)N_NODES;
      float mu = stats[t] * inv;
      float var = stats[128 + t] * inv - mu * mu;
      float s = rsqrtf(var + EPS) * g[t];
      scA[t] = s;
      shA[t] = bb[t] - mu * s;
    }
    __syncthreads();
#pragma unroll
    for (int j = 0; j < 8; ++j) { scR[j] = scA[sub * 8 + j]; shR[j] = shA[sub * 8 + j]; }
  }
  int wave = t >> 6;
  int node = blockIdx.x * 4 + wave;
  if (node >= N_NODES) return;
  int q = lane >> 4;    // quarter 0..3 — each quarter walks edges s0+q, s0+q+4, ...
  int s0 = row_start[node], s1 = row_start[node + 1];
  const uint4* hp = (const uint4*)X;  // row = 16 uint4
  float a[8];
#pragma unroll
  for (int j = 0; j < 8; ++j) a[j] = 0.f;
  int e = s0 + q;
  for (; e + 4 < s1; e += 8) {
    int c0 = col[e];
    int c1 = col[e + 4];
    float on0 = out_norm[c0];
    float on1 = out_norm[c1];
    uint4 u0 = hp[(size_t)c0 * 16 + sub];
    uint4 u1 = hp[(size_t)c1 * 16 + sub];
    const __half2* h0 = (const __half2*)&u0;
    const __half2* h1 = (const __half2*)&u1;
#pragma unroll
    for (int j = 0; j < 4; ++j) {
      float2 f0 = __half22float2(h0[j]);
      float2 f1 = __half22float2(h1[j]);
      if constexpr (BN) {
        f0.x = fmaxf(f0.x * scR[2 * j] + shR[2 * j], 0.f);
        f0.y = fmaxf(f0.y * scR[2 * j + 1] + shR[2 * j + 1], 0.f);
        f1.x = fmaxf(f1.x * scR[2 * j] + shR[2 * j], 0.f);
        f1.y = fmaxf(f1.y * scR[2 * j + 1] + shR[2 * j + 1], 0.f);
      }
      a[2 * j] += on0 * f0.x + on1 * f1.x;
      a[2 * j + 1] += on0 * f0.y + on1 * f1.y;
    }
  }
  if (e < s1) {
    int c = col[e];
    float on = out_norm[c];
    uint4 u = hp[(size_t)c * 16 + sub];
    const __half2* h0 = (const __half2*)&u;
#pragma unroll
    for (int j = 0; j < 4; ++j) {
      float2 f = __half22float2(h0[j]);
      if constexpr (BN) {
        f.x = fmaxf(f.x * scR[2 * j] + shR[2 * j], 0.f);
        f.y = fmaxf(f.y * scR[2 * j + 1] + shR[2 * j + 1], 0.f);
      }
      a[2 * j] += on * f.x;
      a[2 * j + 1] += on * f.y;
    }
  }
  // combine quarters (same sub -> same row components)
#pragma unroll
  for (int j = 0; j < 8; ++j) {
    a[j] += __shfl_xor(a[j], 16);
    a[j] += __shfl_xor(a[j], 32);
  }
  if (q == 0) {
    float sc = in_norm[node];
    __half2 o[4];
#pragma unroll
    for (int j = 0; j < 4; ++j)
      o[j] = __float22half2_rn(make_float2(a[2 * j] * sc, a[2 * j + 1] * sc));
    ((uint4*)out16)[(size_t)node * 16 + sub] = *(const uint4*)o;
  }
}

// ---------------- MFMA dual GEMM + fused BN stats (r7 proven config: BM=64, 256 thr).
// Phase 0: A = Xa (aggregated, final). Phase 1: A = act(Xh) with act = BN+ReLU if BN.
// Direct-global A loads; weights LDS-staged; LDS-transpose coalesced epilogue.
template<int BN>
__launch_bounds__(256)
__global__ void k_gemm_dual16(const unsigned short* __restrict__ Xa,
                              const unsigned short* __restrict__ Xh,
                              const float* __restrict__ stats,
                              const float* __restrict__ g, const float* __restrict__ bb,
                              const unsigned short* __restrict__ W16,  // [2][128][128] fp16
                              unsigned short* __restrict__ Out16, float* __restrict__ pstats) {
  __shared__ __align__(16) unsigned short smem[128 * 136];  // sW compute / sT+stats epilogue
  __shared__ float scA[128], shA[128];
  int t = threadIdx.x;
  int row0 = blockIdx.x * 64;
  int w = t >> 6, lane = t & 63;
  int q = lane >> 4, m = lane & 15;
  if (BN && t < 128) {
    const float inv = 1.f / (float)N_NODES;
    float mu = stats[t] * inv;
    float var = stats[128 + t] * inv - mu * mu;
    float s = rsqrtf(var + EPS) * g[t];
    scA[t] = s;
    shA[t] = bb[t] - mu * s;
  }
  size_t arow = (size_t)min(row0 + w * 16 + m, N_NODES - 1);
  floatx4 acc[8];
#pragma unroll
  for (int i = 0; i < 8; ++i) acc[i] = (floatx4){0.f, 0.f, 0.f, 0.f};

  for (int phase = 0; phase < 2; ++phase) {
    const unsigned short* Xg = phase ? Xh : Xa;
    const uint4* xr = (const uint4*)Xg + arow * 16 + q;   // + ks*4
    uint4 av[4];
    av[0] = xr[0]; av[1] = xr[4]; av[2] = xr[8]; av[3] = xr[12];  // in flight over staging
    __syncthreads();  // phase 1: previous sW reads done; also orders scA writes
    {
      const uint4* wsrc = (const uint4*)(W16 + ((size_t)phase << 14));
#pragma unroll
      for (int it = 0; it < 8; ++it) {
        int idx = it * 256 + t;          // 0..2047, fully coalesced
        *(uint4*)&smem[(idx >> 4) * 136 + (idx & 15) * 8] = wsrc[idx];
      }
    }
    if (BN && phase == 1) {
#pragma unroll
      for (int ks = 0; ks < 4; ++ks) {
        int kk = ks * 32 + q * 8;
        __half2* hh = (__half2*)&av[ks];
#pragma unroll
        for (int j = 0; j < 4; ++j) {
          float2 f = __half22float2(hh[j]);
          f.x = fmaxf(f.x * scA[kk + 2 * j] + shA[kk + 2 * j], 0.f);
          f.y = fmaxf(f.y * scA[kk + 2 * j + 1] + shA[kk + 2 * j + 1], 0.f);
          hh[j] = __float22half2_rn(f);
        }
      }
    }
    __syncthreads();
#pragma unroll
    for (int ks = 0; ks < 4; ++ks) {
      half8 a = *(half8*)&av[ks];
      int kk = ks * 32 + q * 8;
#pragma unroll
      for (int t8 = 0; t8 < 8; ++t8) {
        half8 b = *(const half8*)&smem[(t8 * 16 + m) * 136 + kk];
        acc[t8] = __builtin_amdgcn_mfma_f32_16x16x32_f16(a, b, acc[t8], 0, 0, 0);
      }
    }
  }
  // BN partial stats (register + shfl)
  float ps[8], pq[8];
#pragma unroll
  for (int t8 = 0; t8 < 8; ++t8) {
    float s = 0.f, sq = 0.f;
#pragma unroll
    for (int i = 0; i < 4; ++i) {
      int row = row0 + w * 16 + q * 4 + i;
      if (row < N_NODES) {
        float v = acc[t8][i];
        s += v; sq += v * v;
      }
    }
    s += __shfl_xor(s, 16);
    s += __shfl_xor(s, 32);
    sq += __shfl_xor(sq, 16);
    sq += __shfl_xor(sq, 32);
    ps[t8] = s; pq[t8] = sq;
  }
  __syncthreads();  // all MFMA reads of sW done -> safe to alias
  // transpose epilogue: sT[64][136] halves + stats region after
  unsigned short* sT = smem;
  float* pSum = (float*)(smem + 8704);   // [4][128]
  float* pSq = pSum + 512;               // [4][128]
#pragma unroll
  for (int t8 = 0; t8 < 8; ++t8) {
    int c = t8 * 16 + m;
#pragma unroll
    for (int i = 0; i < 4; ++i) {
      int r = w * 16 + q * 4 + i;
      sT[r * 136 + c] = __half_as_ushort(__float2half_rn(acc[t8][i]));
    }
    if (q == 0) {
      pSum[w * 128 + c] = ps[t8];
      pSq[w * 128 + c] = pq[t8];
    }
  }
  __syncthreads();
  // coalesced uint4 stores (4 per thread)
#pragma unroll
  for (int it = 0; it < 4; ++it) {
    int idx = it * 256 + t;
    int r = idx >> 4, gg = idx & 15;
    int row = row0 + r;
    if (row < N_NODES)
      *(uint4*)&Out16[(size_t)row * 128 + gg * 8] = *(const uint4*)&sT[r * 136 + gg * 8];
  }
  if (t < 128) {
    float s = (pSum[t] + pSum[128 + t]) + (pSum[256 + t] + pSum[384 + t]);
    float sq = (pSq[t] + pSq[128 + t]) + (pSq[256 + t] + pSq[384 + t]);
    pstats[(size_t)blockIdx.x * 256 + t] = s;          // non-atomic per-block partials
    pstats[(size_t)blockIdx.x * 256 + 128 + t] = sq;
  }
}

// ---------------- stats reduction: [nblk][256] -> [256]
__global__ void k_stats_red(const float* __restrict__ pstats, float* __restrict__ stats,
                            int nblk) {
  int t = threadIdx.x;
  float s = 0.f;
  for (int b = blockIdx.x; b < nblk; b += gridDim.x)
    s += pstats[(size_t)b * 256 + t];
  atomicAdd(&stats[t], s);  // 32 blocks x 256 = 8K atomics total, negligible
}

// ---------------- MFMA layer-2 GEMM on h2 = BN+ReLU(P1) (folded):
//   p = fp16(out_norm*(h2@w2^T)) [stride 64, zero-padded]; out = h2@l2^T + b2.
__launch_bounds__(256)
__global__ void k_gemm2_16(const unsigned short* __restrict__ X,  // P1 pre-BN
                           const float* __restrict__ stats,
                           const float* __restrict__ g, const float* __restrict__ bb,
                           const unsigned short* __restrict__ W80,  // [80][128] fp16: w2 then l2
                           const float* __restrict__ b2,
                           const float* __restrict__ out_norm,
                           __half* __restrict__ p, float* __restrict__ out) {
  __shared__ __align__(16) unsigned short smem[80 * 136];  // sW compute / sTp+sTo epilogue
  __shared__ float scA[128], shA[128];
  int t = threadIdx.x;
  int row0 = blockIdx.x * 64;
  int w = t >> 6, lane = t & 63;
  int q = lane >> 4, m = lane & 15;
  if (t < 128) {
    const float inv = 1.f / (float)N_NODES;
    float mu = stats[t] * inv;
    float var = stats[128 + t] * inv - mu * mu;
    float s = rsqrtf(var + EPS) * g[t];
    scA[t] = s;
    shA[t] = bb[t] - mu * s;
  }
  size_t arow = (size_t)min(row0 + w * 16 + m, N_NODES - 1);
  const uint4* xr = (const uint4*)X + arow * 16 + q;
  uint4 av[4];
  av[0] = xr[0]; av[1] = xr[4]; av[2] = xr[8]; av[3] = xr[12];
  {
    const uint4* wsrc = (const uint4*)W80;  // 80*16 = 1280 uint4
#pragma unroll
    for (int it = 0; it < 5; ++it) {
      int idx = it * 256 + t;
      *(uint4*)&smem[(idx >> 4) * 136 + (idx & 15) * 8] = wsrc[idx];
    }
  }
  __syncthreads();
  // fold BN+ReLU into A-fragments
#pragma unroll
  for (int ks = 0; ks < 4; ++ks) {
    int kk = ks * 32 + q * 8;
    __half2* hh = (__half2*)&av[ks];
#pragma unroll
    for (int j = 0; j < 4; ++j) {
      float2 f = __half22float2(hh[j]);
      f.x = fmaxf(f.x * scA[kk + 2 * j] + shA[kk + 2 * j], 0.f);
      f.y = fmaxf(f.y * scA[kk + 2 * j + 1] + shA[kk + 2 * j + 1], 0.f);
      hh[j] = __float22half2_rn(f);
    }
  }
  floatx4 acc[5];
#pragma unroll
  for (int i = 0; i < 5; ++i) acc[i] = (floatx4){0.f, 0.f, 0.f, 0.f};
#pragma unroll
  for (int ks = 0; ks < 4; ++ks) {
    half8 a = *(half8*)&av[ks];
    int kk = ks * 32 + q * 8;
#pragma unroll
    for (int t5 = 0; t5 < 5; ++t5) {
      half8 b = *(const half8*)&smem[(t5 * 16 + m) * 136 + kk];
      acc[t5] = __builtin_amdgcn_mfma_f32_16x16x32_f16(a, b, acc[t5], 0, 0, 0);
    }
  }
  __syncthreads();  // sW reads done -> alias
  unsigned short* sTp = smem;               // [64][72] halves (p rows, 16B-aligned rows)
  float* sTo = (float*)(smem + 4608);       // [64][44] floats (out rows)
  // zero p-pad cols 40..63 (words 20..31 per row)
  {
    unsigned int* zp = (unsigned int*)sTp;
    for (int idx = t; idx < 768; idx += 256) {
      int r = idx / 12, wc = 20 + idx % 12;
      zp[r * 36 + wc] = 0u;
    }
  }
  // transpose writes
  float on4[4];
#pragma unroll
  for (int i = 0; i < 4; ++i) {
    int row = row0 + w * 16 + q * 4 + i;
    on4[i] = out_norm[min(row, N_NODES - 1)];
  }
#pragma unroll
  for (int t5 = 0; t5 < 5; ++t5) {
    int c = t5 * 16 + m;
#pragma unroll
    for (int i = 0; i < 4; ++i) {
      int r = w * 16 + q * 4 + i;
      if (c < 40) {
        sTp[r * 72 + c] = __half_as_ushort(__float2half_rn(on4[i] * acc[t5][i]));
      } else {
        sTo[r * 44 + (c - 40)] = acc[t5][i] + b2[c - 40];
      }
    }
  }
  __syncthreads();
  // coalesced stores: p rows = 8 uint4 (cols 0..63 incl. zero pad)
#pragma unroll
  for (int it = 0; it < 2; ++it) {
    int idx = it * 256 + t;               // 0..511
    int r = idx >> 3, gg = idx & 7;
    int row = row0 + r;
    if (row < N_NODES)
      *(uint4*)((unsigned short*)p + (size_t)row * 64 + gg * 8) = *(const uint4*)&sTp[r * 72 + gg * 8];
  }
  // out rows = 10 float4
  for (int it = 0; it < 3; ++it) {
    int idx = it * 256 + t;               // 0..767, guard 640
    if (idx < 640) {
      int r = idx / 10, gg = idx % 10;
      int row = row0 + r;
      if (row < N_NODES)
        *(float4*)(out + (size_t)row * 40 + gg * 4) = *(const float4*)&sTo[r * 44 + gg * 4];
    }
  }
}

// ---------------- layer-2 aggregation (octet uint4 gather on 128B padded rows):
// out[d] += in_norm[d] * sum_e p[src]. 8 lanes x 16B = one row; 8 edges per instruction.
__global__ void k_agg64h(const __half* __restrict__ p, const int* __restrict__ col,
                         const int* __restrict__ row_start,
                         const float* __restrict__ in_norm,
                         float* __restrict__ out) {
  int wave = threadIdx.x >> 6, lane = threadIdx.x & 63;
  int node = blockIdx.x * 4 + wave;
  if (node >= N_NODES) return;
  int oct = lane >> 3;  // 8 octets, each walks edges s0+oct, s0+oct+8, ...
  int sub = lane & 7;   // 8 lanes x 16B cover the 128B row
  int s0 = row_start[node], s1 = row_start[node + 1];
  const uint4* pp = (const uint4*)p;  // row = 8 uint4
  float a[8];
#pragma unroll
  for (int j = 0; j < 8; ++j) a[j] = 0.f;
  int e = s0 + oct;
  for (; e + 8 < s1; e += 16) {
    int c0 = col[e];
    int c1 = col[e + 8];
    uint4 u0 = pp[(size_t)c0 * 8 + sub];
    uint4 u1 = pp[(size_t)c1 * 8 + sub];
    const __half2* h0 = (const __half2*)&u0;
    const __half2* h1 = (const __half2*)&u1;
#pragma unroll
    for (int j = 0; j < 4; ++j) {
      float2 f0 = __half22float2(h0[j]);
      float2 f1 = __half22float2(h1[j]);
      a[2 * j] += f0.x + f1.x;
      a[2 * j + 1] += f0.y + f1.y;
    }
  }
  if (e < s1) {
    uint4 u = pp[(size_t)col[e] * 8 + sub];
    const __half2* h0 = (const __half2*)&u;
#pragma unroll
    for (int j = 0; j < 4; ++j) {
      float2 f = __half22float2(h0[j]);
      a[2 * j] += f.x;
      a[2 * j + 1] += f.y;
    }
  }
  // combine octets (shfl strides 8/16/32 preserve sub)
#pragma unroll
  for (int j = 0; j < 8; ++j) {
    a[j] += __shfl_xor(a[j], 8);
    a[j] += __shfl_xor(a[j], 16);
    a[j] += __shfl_xor(a[j], 32);
  }
  if (oct == 0 && sub < 5) {  // cols [sub*8, sub*8+8) < 40
    float sc = in_norm[node];
    float4* op = (float4*)(out + (size_t)node * 40 + (size_t)sub * 8);
    float4 v0 = op[0], v1 = op[1];
    v0.x += sc * a[0]; v0.y += sc * a[1]; v0.z += sc * a[2]; v0.w += sc * a[3];
    v1.x += sc * a[4]; v1.y += sc * a[5]; v1.z += sc * a[6]; v1.w += sc * a[7];
    op[0] = v0; op[1] = v1;
  }
}

extern "C" void kernel_launch(void* const* d_in, const int* in_sizes, int n_in,
                              void* d_out, int out_size, void* d_ws, size_t ws_size,
                              hipStream_t stream) {
  const float* feat = (const float*)d_in[0];
  const int* src = (const int*)d_in[1];
  const int* dst = (const int*)d_in[2];
  const float* w0 = (const float*)d_in[3];
  const float* w1 = (const float*)d_in[4];
  const float* w2 = (const float*)d_in[5];
  const float* b2 = (const float*)d_in[6];
  const float* l0 = (const float*)d_in[7];
  const float* l1 = (const float*)d_in[8];
  const float* l2 = (const float*)d_in[9];
  const float* g0 = (const float*)d_in[10];
  const float* beta0 = (const float*)d_in[11];
  const float* g1 = (const float*)d_in[12];
  const float* beta1 = (const float*)d_in[13];
  float* out = (float*)d_out;

  char* ws = (char*)d_ws;
  size_t off = 0;
  auto alloc = [&](size_t bytes) {
    void* ptr = ws + off;
    off = (off + bytes + 255) & ~(size_t)255;
    return ptr;
  };
  unsigned short* A16 = (unsigned short*)alloc(2 * (size_t)N_NODES * 128);  // agg out / p (64-stride)
  float* B = (float*)alloc(sizeof(float) * (size_t)N_NODES * 128);          // Hparts (prep) / P0
  unsigned short* F = (unsigned short*)alloc(2 * (size_t)N_NODES * 128);    // feat fp16 / P1
  int* degd = (int*)alloc(sizeof(int) * N_NODES);
  int* row_start = (int*)alloc(sizeof(int) * (N_NODES + 1));
  int* colb = (int*)alloc(sizeof(int) * N_EDGES);
  float* out_norm = (float*)alloc(sizeof(float) * N_NODES);
  float* in_norm = (float*)alloc(sizeof(float) * N_NODES);
  int* bsum = (int*)alloc(sizeof(int) * 512);
  float* stats0 = (float*)alloc(sizeof(float) * 256);
  float* stats1 = (float*)alloc(sizeof(float) * 256);
  unsigned short* W16 = (unsigned short*)alloc(2 * (size_t)75776);          // fp16 weights
  int gb = (N_NODES + 63) / 64;  // 1563
  float* pstats = (float*)alloc(sizeof(float) * (size_t)gb * 256);          // BN partials

  // Two Hpart tables (16.8 MB each) alias B (51.2 MB); consumed before P0's first write.
  unsigned int* Hs = (unsigned int*)B;            // src histogram
  unsigned int* Hd = Hs + (size_t)HCH * HRG * HWORDS;  // dst histogram (scanned -> bases)
  unsigned short* P0 = (unsigned short*)B;        // layer-0 pre-BN gemm out
  unsigned short* P1 = F;                         // layer-1 pre-BN gemm out (F dead by then)

  int nb = (N_NODES + 255) / 256;  // 391
  int hb = HCH * HRG;              // 256

  k_w2h<<<74, 256, 0, stream>>>(w0, l0, w1, l1, w2, l2, W16);

  k_hist_both<<<2 * hb, 256, 0, stream>>>(src, dst, Hs, Hd);
  k_hist_scan2<<<nb, 256, 0, stream>>>((const unsigned short*)Hs, (unsigned short*)Hd,
                                       degd, out_norm, in_norm, bsum);
  k_scan2<<<1, 512, 0, stream>>>(bsum, nb);
  k_scan3<<<nb, 256, 0, stream>>>(degd, bsum, row_start);
  k_build<<<hb, 256, 0, stream>>>(src, dst, (const unsigned short*)Hd, row_start, colb);

  int ab = (N_NODES + 3) / 4;   // wave per node
  int fb = (N_NODES * 32 + 255) / 256;

  // layer 0: P0 = agg(feat)@w0^T + feat@l0^T   (pre-BN; stats accumulated)
  k_feat2h<<<fb, 256, 0, stream>>>(feat, F);
  k_agg128h<0><<<ab, 256, 0, stream>>>(F, colb, row_start, out_norm, in_norm,
                                       nullptr, nullptr, nullptr, A16);
  k_gemm_dual16<0><<<gb, 256, 0, stream>>>(A16, F, nullptr, nullptr, nullptr,
                                           W16, P0, pstats);
  hipMemsetAsync(stats0, 0, sizeof(float) * 256, stream);
  k_stats_red<<<32, 256, 0, stream>>>(pstats, stats0, gb);

  // layer 1: h1 = relu(bn(P0)) folded into consumers; P1 = agg(h1)@w1^T + h1@l1^T
  k_agg128h<1><<<ab, 256, 0, stream>>>(P0, colb, row_start, out_norm, in_norm,
                                       stats0, g0, beta0, A16);
  k_gemm_dual16<1><<<gb, 256, 0, stream>>>(A16, P0, stats0, g0, beta0,
                                           W16 + 32768, P1, pstats);
  hipMemsetAsync(stats1, 0, sizeof(float) * 256, stream);
  k_stats_red<<<32, 256, 0, stream>>>(pstats, stats1, gb);

  // layer 2: h2 = relu(bn(P1)) folded; out = in_norm*agg(fp16(out_norm*(h2@w2^T))) + b2 + h2@l2^T
  __half* p = (__half*)A16;  // A16 dead after layer-1 gemm; p is [N][64] fp16
  k_gemm2_16<<<gb, 256, 0, stream>>>(P1, stats1, g1, beta1, W16 + 65536, b2, out_norm, p, out);
  k_agg64h<<<ab, 256, 0, stream>>>(p, colb, row_start, in_norm, out);
}